// Round 3
// baseline (459.468 us; speedup 1.0000x reference)
//
#include <hip/hip_runtime.h>

#define BB 2
#define SS 2048
#define EE 2048
#define HH 16
#define DD 128
#define SE (3 * EE)  // QKV row stride

typedef __bf16 bf16x8 __attribute__((ext_vector_type(8)));
typedef unsigned short u16x8 __attribute__((ext_vector_type(8)));
typedef float f32x4 __attribute__((ext_vector_type(4)));

__device__ __forceinline__ unsigned short f32_to_bf16(float f) {
  unsigned int u = __builtin_bit_cast(unsigned int, f);
  u += 0x7FFFu + ((u >> 16) & 1u);  // RNE
  return (unsigned short)(u >> 16);
}

__device__ __forceinline__ void gll16(const void* g, const void* lds) {
  __builtin_amdgcn_global_load_lds(
      (const __attribute__((address_space(1))) unsigned int*)g,
      (__attribute__((address_space(3))) unsigned int*)lds, 16, 0, 0);
}

__device__ __forceinline__ bf16x8 lds_frag(const unsigned short* p) {
  return __builtin_bit_cast(bf16x8, *(const u16x8*)p);
}

// ---------------- cast x: fp32 -> bf16 ----------------
__global__ void k_cast_bf16(const float* __restrict__ x, unsigned short* __restrict__ y) {
  int i = blockIdx.x * 256 + threadIdx.x;
  float4 v = ((const float4*)x)[i];
  ushort4 o;
  o.x = f32_to_bf16(v.x); o.y = f32_to_bf16(v.y);
  o.z = f32_to_bf16(v.z); o.w = f32_to_bf16(v.w);
  ((ushort4*)y)[i] = o;
}

// ---- all four W [E,E] fp32 -> Wt [E,E] bf16 (transposed), z selects ----
__global__ void k_transpose_w4(const float* __restrict__ W0, const float* __restrict__ W1,
                               const float* __restrict__ W2, const float* __restrict__ W3,
                               unsigned short* __restrict__ WtBase) {
  const float* W = blockIdx.z == 0 ? W0 : blockIdx.z == 1 ? W1 : blockIdx.z == 2 ? W2 : W3;
  unsigned short* Wt = WtBase + (size_t)blockIdx.z * EE * EE;
  __shared__ float tile[32][33];
  int n0 = blockIdx.x * 32, k0 = blockIdx.y * 32;
  int t = threadIdx.x, r = t >> 5, c = t & 31;
  for (int i = 0; i < 32; i += 8)
    tile[r + i][c] = W[(size_t)(k0 + r + i) * EE + n0 + c];
  __syncthreads();
  for (int i = 0; i < 32; i += 8)
    Wt[(size_t)(n0 + r + i) * EE + k0 + c] = f32_to_bf16(tile[c][r + i]);
}

// ---- per-head transpose: QKV[b*S+s][2E + h*D+d] -> Vt[(bh*D+d)*S+s] ----
__global__ void k_transpose_v(const unsigned short* __restrict__ QKV, unsigned short* __restrict__ Vt) {
  __shared__ unsigned short tile[32][33];
  int s0 = blockIdx.x * 32, d0 = blockIdx.y * 32, bh = blockIdx.z;
  int b = bh >> 4, h = bh & 15;
  int t = threadIdx.x, r = t >> 5, c = t & 31;
  for (int i = 0; i < 32; i += 8)
    tile[r + i][c] = QKV[(size_t)(b * SS + s0 + r + i) * SE + 2 * EE + h * DD + d0 + c];
  __syncthreads();
  for (int i = 0; i < 32; i += 8)
    Vt[(size_t)(bh * DD + d0 + r + i) * SS + s0 + c] = tile[c][r + i];
}

// ---------------- GEMM: C[M,N] = A[M,K] @ Bt[N,K]^T ----
// R0 structure (128x128, BK=64, XOR chunk swizzle, 0 conflicts measured)
// + T3 minimum 2-phase: double-buffered LDS (64 KB -> 2 blocks/CU), stage
// tile t+1 into buf^1 BEFORE computing tile t; one vmcnt(0)+barrier per
// K-tile (inside __syncthreads). Load latency overlaps the ds_read+MFMA
// region instead of being serially exposed (R0 issued loads then drained
// them immediately). Layout/swizzle/fragment math byte-identical to R0.
template <int OUTF32>
__global__ __launch_bounds__(256, 2) void k_gemm_bt(
    const unsigned short* __restrict__ A, const unsigned short* __restrict__ Bt,
    void* __restrict__ Cout, const float* __restrict__ bias, int K, int N) {
  __shared__ unsigned short As[2 * 128 * 64];  // 2 x 16 KB
  __shared__ unsigned short Bs[2 * 128 * 64];  // 2 x 16 KB
  const int tid = threadIdx.x;
  const int l = tid & 63, w = tid >> 6;
  const int m0 = blockIdx.y * 128, n0 = blockIdx.x * 128;
  const int tm = l & 15, qc = l >> 4;
  const int swz = tm & 7;
  const int m_base = (w >> 1) * 64, n_base = (w & 1) * 64;
  f32x4 acc[4][4] = {};

  // loop-invariant staging addresses (same mapping as R0's in-loop calc)
  const unsigned short* srcA[4];
  const unsigned short* srcB[4];
  int ldsOff[4];
  for (int is = 0; is < 4; ++is) {
    int idx = (w * 4 + is) * 64 + l;            // [0,1024)
    int row = idx >> 3, c = (idx & 7) ^ (row & 7);
    srcA[is] = A + (size_t)(m0 + row) * K + c * 8;
    srcB[is] = Bt + (size_t)(n0 + row) * K + c * 8;
    ldsOff[is] = idx * 16;                      // linear LDS byte offset
  }
  const int NT = K >> 6;

  // prologue: stage tile 0 into buf 0
  for (int is = 0; is < 4; ++is) {
    gll16(srcA[is], (char*)As + ldsOff[is]);
    gll16(srcB[is], (char*)Bs + ldsOff[is]);
  }
  __syncthreads();

  for (int t = 0; t < NT; ++t) {
    const int cur = t & 1;
    if (t + 1 < NT) {
      const int ko = (t + 1) * 64;
      char* Ad = (char*)As + (cur ^ 1) * 16384;
      char* Bd = (char*)Bs + (cur ^ 1) * 16384;
      for (int is = 0; is < 4; ++is) {
        gll16(srcA[is] + ko, Ad + ldsOff[is]);
        gll16(srcB[is] + ko, Bd + ldsOff[is]);
      }
    }
    const unsigned short* Ab = As + cur * 8192;
    const unsigned short* Bb = Bs + cur * 8192;
    for (int ks = 0; ks < 2; ++ks) {
      bf16x8 a[4], b[4];
      for (int im = 0; im < 4; ++im)
        a[im] = lds_frag(&Ab[(m_base + im * 16 + tm) * 64 + (((ks * 4 + qc) ^ swz) << 3)]);
      for (int in = 0; in < 4; ++in)
        b[in] = lds_frag(&Bb[(n_base + in * 16 + tm) * 64 + (((ks * 4 + qc) ^ swz) << 3)]);
      __builtin_amdgcn_s_setprio(1);
      for (int im = 0; im < 4; ++im)
        for (int in = 0; in < 4; ++in)
          acc[im][in] = __builtin_amdgcn_mfma_f32_16x16x32_bf16(a[im], b[in], acc[im][in], 0, 0, 0);
      __builtin_amdgcn_s_setprio(0);
    }
    __syncthreads();  // vmcnt(0)+lgkmcnt(0)+barrier: next tile landed, cur free
  }

  for (int im = 0; im < 4; ++im)
    for (int in = 0; in < 4; ++in)
      for (int r = 0; r < 4; ++r) {
        int row = m0 + m_base + im * 16 + (l >> 4) * 4 + r;
        int col = n0 + n_base + in * 16 + tm;
        if (OUTF32)
          ((float*)Cout)[(size_t)row * N + col] = acc[im][in][r] + bias[col];
        else
          ((unsigned short*)Cout)[(size_t)row * N + col] = f32_to_bf16(acc[im][in][r]);
      }
}

// ---------------- flash-style causal attention with ALiBi ----
// R0 structure + three low-risk changes:
//  (1) T5 setprio(1) around QK^T and PV MFMA clusters (+4-7% attn, m191)
//  (2) V ds_reads hoisted into the kn loop (overlap QK^T MFMA/VALU instead
//      of sitting on the P->PV critical path after lgkmcnt(0))
//  (3) ALiBi per-element VALU hoisted: slopeL*(j-ibase) once per (kn,im)
__global__ __launch_bounds__(256, 2) void k_attn(
    const unsigned short* __restrict__ QKV, const unsigned short* __restrict__ Vt,
    unsigned short* __restrict__ ctx) {
  __shared__ unsigned short smem[40960];  // 80 KB
  const int tid = threadIdx.x;
  const int l = tid & 63, w = tid >> 6;
  const int tm = l & 15, qc = l >> 4;
  const int bh = blockIdx.x, b = bh >> 4, h = bh & 15;
  const int rank = blockIdx.y;
  const int t = (rank < 8) ? (15 - rank) : (rank - 8);
  const int q0 = t * 128;
  const int n_it = 2 * t + 2;
  const float c1 = 0.12751676f;  // log2(e)/sqrt(128)
  const float slopeL = exp2f(-0.5f * (float)(h + 1)) * c1;
  const float sr1 = slopeL, sr2 = slopeL * 2.0f, sr3 = slopeL * 3.0f;

  const unsigned short* Qg = QKV + h * DD;
  const unsigned short* Kg = QKV + EE + h * DD;
  const unsigned short* Vg = Vt + (size_t)bh * DD * SS;
  unsigned short* Ps = smem + 32768 + w * 2048;

  for (int is = 0; is < 8; ++is) {
    int idx = (w * 8 + is) * 64 + l;
    int row = idx >> 4, c = (idx & 15) ^ (row & 7);
    gll16(&Qg[(size_t)(b * SS + q0 + row) * SE + c * 8], ((char*)smem) + 32768 + idx * 16);
  }
  for (int is = 0; is < 4; ++is) {
    int idx = (w * 4 + is) * 64 + l;
    int kr = idx >> 4, kc = (idx & 15) ^ (kr & 7);
    gll16(&Kg[(size_t)(b * SS + kr) * SE + kc * 8], ((char*)smem) + idx * 16);
    int vr = idx >> 3, vc = (idx & 7) ^ (vr & 7);
    gll16(&Vg[(size_t)vr * SS + vc * 8], ((char*)smem) + 16384 + idx * 16);
  }
  __syncthreads();
  bf16x8 qf[2][4];
  for (int im = 0; im < 2; ++im)
    for (int kk = 0; kk < 4; ++kk) {
      int row = w * 32 + im * 16 + tm;
      qf[im][kk] = lds_frag(&smem[16384 + (row * 16 + ((kk * 4 + qc) ^ (tm & 7))) * 8]);
    }
  __syncthreads();

  float lr[2][4] = {};
  f32x4 o[2][8] = {};

  for (int it = 0; it < n_it; ++it) {
    const int kt = it * 64;
    const unsigned short* K_ = smem + (it & 1) * 16384;
    const unsigned short* V_ = K_ + 8192;
    if (it + 1 < n_it) {
      char* Kd = ((char*)smem) + ((it + 1) & 1) * 32768;
      int ktn = kt + 64;
      for (int is = 0; is < 4; ++is) {
        int idx = (w * 4 + is) * 64 + l;
        int kr = idx >> 4, kc = (idx & 15) ^ (kr & 7);
        gll16(&Kg[(size_t)(b * SS + ktn + kr) * SE + kc * 8], Kd + idx * 16);
        int vr = idx >> 3, vc = (idx & 7) ^ (vr & 7);
        gll16(&Vg[(size_t)vr * SS + ktn + vc * 8], Kd + 16384 + idx * 16);
      }
    }
    const bool full = (kt + 64 <= q0);

    bf16x8 vf0[8], vf1[8];
#pragma unroll
    for (int kn = 0; kn < 4; ++kn) {
      bf16x8 kf[4];
#pragma unroll
      for (int kk = 0; kk < 4; ++kk) {
        int row = kn * 16 + tm;
        kf[kk] = lds_frag(&K_[(row * 16 + ((kk * 4 + qc) ^ (tm & 7))) * 8]);
      }
      // hoisted V reads: 2 dc rows per kn -> full V tile in regs by kn=3
      {
        const int dcA = kn * 2, dcB = kn * 2 + 1;
        const int vrA = dcA * 16 + tm, vrB = dcB * 16 + tm;
        vf0[dcA] = lds_frag(&V_[(vrA * 8 + (qc ^ (tm & 7))) * 8]);
        vf1[dcA] = lds_frag(&V_[(vrA * 8 + ((4 + qc) ^ (tm & 7))) * 8]);
        vf0[dcB] = lds_frag(&V_[(vrB * 8 + (qc ^ (tm & 7))) * 8]);
        vf1[dcB] = lds_frag(&V_[(vrB * 8 + ((4 + qc) ^ (tm & 7))) * 8]);
      }
      f32x4 a0 = {}, a1 = {};
      __builtin_amdgcn_s_setprio(1);
#pragma unroll
      for (int kk = 0; kk < 4; ++kk) {
        a0 = __builtin_amdgcn_mfma_f32_16x16x32_bf16(qf[0][kk], kf[kk], a0, 0, 0, 0);
        a1 = __builtin_amdgcn_mfma_f32_16x16x32_bf16(qf[1][kk], kf[kk], a1, 0, 0, 0);
      }
      __builtin_amdgcn_s_setprio(0);
      const int j = kt + kn * 16 + tm;
#pragma unroll
      for (int im = 0; im < 2; ++im) {
        const f32x4 av = im ? a1 : a0;
        const int ibase = q0 + w * 32 + im * 16 + qc * 4;
        const int dj = j - ibase;                 // d for r=0
        const float bse = slopeL * (float)dj;
#pragma unroll
        for (int r = 0; r < 4; ++r) {
          const float srr = (r == 0) ? 0.0f : (r == 1) ? sr1 : (r == 2) ? sr2 : sr3;
          float arg = av[r] * c1 + (bse - srr);
          if (!full && dj > r) arg = -1e30f;
          float p = __builtin_amdgcn_exp2f(arg);
          lr[im][r] += p;
          unsigned int u = __builtin_bit_cast(unsigned int, p);
          int prow = im * 16 + qc * 4 + r;
          int pslot = (kn * 2 + (tm >> 3)) ^ (prow & 7);
          Ps[(prow * 8 + pslot) * 8 + (tm & 7)] = (unsigned short)(u >> 16);
        }
      }
    }
    asm volatile("s_waitcnt lgkmcnt(0)" ::: "memory");
    bf16x8 pf[2][2];
#pragma unroll
    for (int im = 0; im < 2; ++im)
#pragma unroll
      for (int k2 = 0; k2 < 2; ++k2) {
        int prow = im * 16 + tm;
        pf[im][k2] = lds_frag(&Ps[(prow * 8 + ((k2 * 4 + qc) ^ (tm & 7))) * 8]);
      }
    __builtin_amdgcn_s_setprio(1);
#pragma unroll
    for (int dc = 0; dc < 8; ++dc) {
      o[0][dc] = __builtin_amdgcn_mfma_f32_16x16x32_bf16(pf[0][0], vf0[dc], o[0][dc], 0, 0, 0);
      o[0][dc] = __builtin_amdgcn_mfma_f32_16x16x32_bf16(pf[0][1], vf1[dc], o[0][dc], 0, 0, 0);
      o[1][dc] = __builtin_amdgcn_mfma_f32_16x16x32_bf16(pf[1][0], vf0[dc], o[1][dc], 0, 0, 0);
      o[1][dc] = __builtin_amdgcn_mfma_f32_16x16x32_bf16(pf[1][1], vf1[dc], o[1][dc], 0, 0, 0);
    }
    __builtin_amdgcn_s_setprio(0);
    __syncthreads();
  }

  for (int im = 0; im < 2; ++im)
    for (int r = 0; r < 4; ++r) {
      float s = lr[im][r];
      for (int off = 8; off >= 1; off >>= 1) s += __shfl_xor(s, off, 64);
      float inv = 1.0f / s;
      int i = q0 + w * 32 + im * 16 + qc * 4 + r;
      for (int dc = 0; dc < 8; ++dc)
        ctx[(size_t)(b * SS + i) * EE + h * DD + dc * 16 + tm] =
            f32_to_bf16(o[im][dc][r] * inv);
    }
}

extern "C" void kernel_launch(void* const* d_in, const int* in_sizes, int n_in,
                              void* d_out, int out_size, void* d_ws, size_t ws_size,
                              hipStream_t stream) {
  const float* x  = (const float*)d_in[0];
  const float* Wq = (const float*)d_in[1];
  const float* Wk = (const float*)d_in[2];
  const float* Wv = (const float*)d_in[3];
  const float* Wo = (const float*)d_in[4];
  const float* bo = (const float*)d_in[5];
  float* out = (float*)d_out;

  const size_t XE = (size_t)BB * SS * EE;
  const size_t WE = (size_t)EE * EE;
  unsigned short* ws   = (unsigned short*)d_ws;
  unsigned short* xb   = ws;            // reused as ctx
  unsigned short* WqT  = xb + XE;       // WqT|WkT|WvT|WoT contiguous
  unsigned short* WoT  = WqT + 3 * WE;
  unsigned short* QKVb = WoT + WE;      // [B*S][3E]
  unsigned short* Vt   = QKVb + 3 * XE;
  unsigned short* ctx  = xb;

  k_cast_bf16<<<XE / 1024, 256, 0, stream>>>(x, xb);
  k_transpose_w4<<<dim3(EE / 32, EE / 32, 4), 256, 0, stream>>>(Wq, Wk, Wv, Wo, WqT);

  dim3 gqkv(SE / 128, (BB * SS) / 128);  // (48, 32)
  k_gemm_bt<0><<<gqkv, 256, 0, stream>>>(xb, WqT, QKVb, nullptr, EE, SE);

  k_transpose_v<<<dim3(SS / 32, DD / 32, BB * HH), 256, 0, stream>>>(QKVb, Vt);
  k_attn<<<dim3(BB * HH, SS / 128), 256, 0, stream>>>(QKVb, Vt, ctx);

  dim3 gg(EE / 128, (BB * SS) / 128);  // (16, 32)
  k_gemm_bt<1><<<gg, 256, 0, stream>>>(ctx, WoT, out, bo, EE, EE);
}

// Round 4
// 341.994 us; speedup vs baseline: 1.3435x; 1.3435x over previous
//
#include <hip/hip_runtime.h>

#define BB 2
#define SS 2048
#define EE 2048
#define HH 16
#define DD 128
#define SE (3 * EE)  // QKV row stride

typedef __bf16 bf16x8 __attribute__((ext_vector_type(8)));
typedef unsigned short u16x8 __attribute__((ext_vector_type(8)));
typedef float f32x4 __attribute__((ext_vector_type(4)));

__device__ __forceinline__ unsigned short f32_to_bf16(float f) {
  unsigned int u = __builtin_bit_cast(unsigned int, f);
  u += 0x7FFFu + ((u >> 16) & 1u);  // RNE
  return (unsigned short)(u >> 16);
}

__device__ __forceinline__ void gll16(const void* g, const void* lds) {
  __builtin_amdgcn_global_load_lds(
      (const __attribute__((address_space(1))) unsigned int*)g,
      (__attribute__((address_space(3))) unsigned int*)lds, 16, 0, 0);
}

__device__ __forceinline__ bf16x8 lds_frag(const unsigned short* p) {
  return __builtin_bit_cast(bf16x8, *(const u16x8*)p);
}

// ---------------- cast x: fp32 -> bf16 ----------------
__global__ void k_cast_bf16(const float* __restrict__ x, unsigned short* __restrict__ y) {
  int i = blockIdx.x * 256 + threadIdx.x;
  float4 v = ((const float4*)x)[i];
  ushort4 o;
  o.x = f32_to_bf16(v.x); o.y = f32_to_bf16(v.y);
  o.z = f32_to_bf16(v.z); o.w = f32_to_bf16(v.w);
  ((ushort4*)y)[i] = o;
}

// ---- all four W [E,E] fp32 -> Wt [E,E] bf16 (transposed), z selects ----
__global__ void k_transpose_w4(const float* __restrict__ W0, const float* __restrict__ W1,
                               const float* __restrict__ W2, const float* __restrict__ W3,
                               unsigned short* __restrict__ WtBase) {
  const float* W = blockIdx.z == 0 ? W0 : blockIdx.z == 1 ? W1 : blockIdx.z == 2 ? W2 : W3;
  unsigned short* Wt = WtBase + (size_t)blockIdx.z * EE * EE;
  __shared__ float tile[32][33];
  int n0 = blockIdx.x * 32, k0 = blockIdx.y * 32;
  int t = threadIdx.x, r = t >> 5, c = t & 31;
  for (int i = 0; i < 32; i += 8)
    tile[r + i][c] = W[(size_t)(k0 + r + i) * EE + n0 + c];
  __syncthreads();
  for (int i = 0; i < 32; i += 8)
    Wt[(size_t)(n0 + r + i) * EE + k0 + c] = f32_to_bf16(tile[c][r + i]);
}

// ---------------- GEMM: C[M,N] = A[M,K] @ Bt[N,K]^T ----
// R0 structure verbatim (128x128, BK=64, XOR chunk swizzle = 0 conflicts,
// single-buffer 2-barrier, launch_bounds(256,4) -> 4 blocks/CU TLP).
// ONLY change: for the QKV call (OUTF32==0), blocks whose n-range lies in
// the V third (n0 >= 2E) write accumulators DIRECTLY to the per-head
// transposed Vt[(bh*D+d)*S+s] as ushort4 (r=0..3 = consecutive s), and
// skip the QKVb V-third write. This deletes k_transpose_v entirely
// (16.7MB read + 16.7MB write + dispatch) and removes 16.7MB of QKVb
// writes. Stores are 8B/lane; im/qc together fill complete 64B lines, so
// L2 write-combining keeps HBM write traffic unchanged for the V region.
template <int OUTF32>
__global__ __launch_bounds__(256, 4) void k_gemm_bt(
    const unsigned short* __restrict__ A, const unsigned short* __restrict__ Bt,
    void* __restrict__ Cout, const float* __restrict__ bias,
    unsigned short* __restrict__ VtOut, int K, int N) {
  __shared__ unsigned short As[128 * 64];
  __shared__ unsigned short Bs[128 * 64];
  const int tid = threadIdx.x;
  const int l = tid & 63, w = tid >> 6;
  const int m0 = blockIdx.y * 128, n0 = blockIdx.x * 128;
  const int tm = l & 15, qc = l >> 4;
  const int swz = tm & 7;
  const int m_base = (w >> 1) * 64, n_base = (w & 1) * 64;
  f32x4 acc[4][4] = {};

  for (int k0 = 0; k0 < K; k0 += 64) {
    for (int is = 0; is < 4; ++is) {
      int o = (w * 4 + is) * 1024 + l * 16;        // byte offset = LDS slot
      int row = o >> 7, slot = (o >> 4) & 7;
      int c = slot ^ (row & 7);                    // global chunk for this slot
      gll16(&A[(size_t)(m0 + row) * K + k0 + c * 8], ((const char*)As) + o);
      gll16(&Bt[(size_t)(n0 + row) * K + k0 + c * 8], ((const char*)Bs) + o);
    }
    __syncthreads();
    for (int ks = 0; ks < 2; ++ks) {
      bf16x8 a[4], b[4];
      for (int im = 0; im < 4; ++im)
        a[im] = lds_frag(&As[(m_base + im * 16 + tm) * 64 + (((ks * 4 + qc) ^ swz) << 3)]);
      for (int in = 0; in < 4; ++in)
        b[in] = lds_frag(&Bs[(n_base + in * 16 + tm) * 64 + (((ks * 4 + qc) ^ swz) << 3)]);
      for (int im = 0; im < 4; ++im)
        for (int in = 0; in < 4; ++in)
          acc[im][in] = __builtin_amdgcn_mfma_f32_16x16x32_bf16(a[im], b[in], acc[im][in], 0, 0, 0);
    }
    __syncthreads();
  }

  if (!OUTF32 && n0 >= 2 * EE) {
    // V third: write per-head transposed directly. col -> (h,d); row -> (b,s).
    for (int im = 0; im < 4; ++im)
      for (int in = 0; in < 4; ++in) {
        int row0 = m0 + m_base + im * 16 + qc * 4;    // s base (4 consecutive)
        int col = n0 + n_base + in * 16 + tm - 2 * EE; // v index in [0,2048)
        int b = row0 >> 11, s = row0 & 2047;
        int h = col >> 7, d = col & 127;
        ushort4 o;
        o.x = f32_to_bf16(acc[im][in][0]);
        o.y = f32_to_bf16(acc[im][in][1]);
        o.z = f32_to_bf16(acc[im][in][2]);
        o.w = f32_to_bf16(acc[im][in][3]);
        *(ushort4*)&VtOut[((size_t)((b * HH + h) * DD + d) << 11) + s] = o;
      }
    return;
  }

  for (int im = 0; im < 4; ++im)
    for (int in = 0; in < 4; ++in)
      for (int r = 0; r < 4; ++r) {
        int row = m0 + m_base + im * 16 + (l >> 4) * 4 + r;
        int col = n0 + n_base + in * 16 + tm;
        if (OUTF32)
          ((float*)Cout)[(size_t)row * N + col] = acc[im][in][r] + bias[col];
        else
          ((unsigned short*)Cout)[(size_t)row * N + col] = f32_to_bf16(acc[im][in][r]);
      }
}

// ---------------- flash-style causal attention with ALiBi (R0 verbatim) ----
__global__ __launch_bounds__(256, 2) void k_attn(
    const unsigned short* __restrict__ QKV, const unsigned short* __restrict__ Vt,
    unsigned short* __restrict__ ctx) {
  __shared__ unsigned short smem[40960];  // 80 KB
  const int tid = threadIdx.x;
  const int l = tid & 63, w = tid >> 6;
  const int tm = l & 15, qc = l >> 4;
  const int bh = blockIdx.x, b = bh >> 4, h = bh & 15;
  const int rank = blockIdx.y;
  const int t = (rank < 8) ? (15 - rank) : (rank - 8);
  const int q0 = t * 128;
  const int n_it = 2 * t + 2;
  const float c1 = 0.12751676f;  // log2(e)/sqrt(128)
  const float slopeL = exp2f(-0.5f * (float)(h + 1)) * c1;

  const unsigned short* Qg = QKV + h * DD;
  const unsigned short* Kg = QKV + EE + h * DD;
  const unsigned short* Vg = Vt + (size_t)bh * DD * SS;
  unsigned short* Ps = smem + 32768 + w * 2048;

  for (int is = 0; is < 8; ++is) {
    int idx = (w * 8 + is) * 64 + l;
    int row = idx >> 4, c = (idx & 15) ^ (row & 7);
    gll16(&Qg[(size_t)(b * SS + q0 + row) * SE + c * 8], ((char*)smem) + 32768 + idx * 16);
  }
  for (int is = 0; is < 4; ++is) {
    int idx = (w * 4 + is) * 64 + l;
    int kr = idx >> 4, kc = (idx & 15) ^ (kr & 7);
    gll16(&Kg[(size_t)(b * SS + kr) * SE + kc * 8], ((char*)smem) + idx * 16);
    int vr = idx >> 3, vc = (idx & 7) ^ (vr & 7);
    gll16(&Vg[(size_t)vr * SS + vc * 8], ((char*)smem) + 16384 + idx * 16);
  }
  __syncthreads();
  bf16x8 qf[2][4];
  for (int im = 0; im < 2; ++im)
    for (int kk = 0; kk < 4; ++kk) {
      int row = w * 32 + im * 16 + tm;
      qf[im][kk] = lds_frag(&smem[16384 + (row * 16 + ((kk * 4 + qc) ^ (tm & 7))) * 8]);
    }
  __syncthreads();

  float lr[2][4] = {};
  f32x4 o[2][8] = {};

  for (int it = 0; it < n_it; ++it) {
    const int kt = it * 64;
    const unsigned short* K_ = smem + (it & 1) * 16384;
    const unsigned short* V_ = K_ + 8192;
    if (it + 1 < n_it) {
      char* Kd = ((char*)smem) + ((it + 1) & 1) * 32768;
      int ktn = kt + 64;
      for (int is = 0; is < 4; ++is) {
        int idx = (w * 4 + is) * 64 + l;
        int kr = idx >> 4, kc = (idx & 15) ^ (kr & 7);
        gll16(&Kg[(size_t)(b * SS + ktn + kr) * SE + kc * 8], Kd + idx * 16);
        int vr = idx >> 3, vc = (idx & 7) ^ (vr & 7);
        gll16(&Vg[(size_t)vr * SS + ktn + vc * 8], Kd + 16384 + idx * 16);
      }
    }
    const bool full = (kt + 64 <= q0);

    for (int kn = 0; kn < 4; ++kn) {
      bf16x8 kf[4];
      for (int kk = 0; kk < 4; ++kk) {
        int row = kn * 16 + tm;
        kf[kk] = lds_frag(&K_[(row * 16 + ((kk * 4 + qc) ^ (tm & 7))) * 8]);
      }
      f32x4 a0 = {}, a1 = {};
      for (int kk = 0; kk < 4; ++kk) {
        a0 = __builtin_amdgcn_mfma_f32_16x16x32_bf16(qf[0][kk], kf[kk], a0, 0, 0, 0);
        a1 = __builtin_amdgcn_mfma_f32_16x16x32_bf16(qf[1][kk], kf[kk], a1, 0, 0, 0);
      }
      const int j = kt + kn * 16 + tm;
      for (int im = 0; im < 2; ++im) {
        const f32x4 av = im ? a1 : a0;
        const int ibase = q0 + w * 32 + im * 16 + qc * 4;
        for (int r = 0; r < 4; ++r) {
          int d = j - (ibase + r);
          float arg = av[r] * c1 + slopeL * (float)d;
          if (!full && d > 0) arg = -1e30f;
          float p = __builtin_amdgcn_exp2f(arg);
          lr[im][r] += p;
          unsigned int u = __builtin_bit_cast(unsigned int, p);
          int prow = im * 16 + qc * 4 + r;
          int pslot = (kn * 2 + (tm >> 3)) ^ (prow & 7);
          Ps[(prow * 8 + pslot) * 8 + (tm & 7)] = (unsigned short)(u >> 16);
        }
      }
    }
    asm volatile("s_waitcnt lgkmcnt(0)" ::: "memory");
    bf16x8 pf[2][2];
    for (int im = 0; im < 2; ++im)
      for (int k2 = 0; k2 < 2; ++k2) {
        int prow = im * 16 + tm;
        pf[im][k2] = lds_frag(&Ps[(prow * 8 + ((k2 * 4 + qc) ^ (tm & 7))) * 8]);
      }
    for (int dc = 0; dc < 8; ++dc) {
      int vrow = dc * 16 + tm;
      bf16x8 vf0 = lds_frag(&V_[(vrow * 8 + (qc ^ (tm & 7))) * 8]);
      bf16x8 vf1 = lds_frag(&V_[(vrow * 8 + ((4 + qc) ^ (tm & 7))) * 8]);
      o[0][dc] = __builtin_amdgcn_mfma_f32_16x16x32_bf16(pf[0][0], vf0, o[0][dc], 0, 0, 0);
      o[0][dc] = __builtin_amdgcn_mfma_f32_16x16x32_bf16(pf[0][1], vf1, o[0][dc], 0, 0, 0);
      o[1][dc] = __builtin_amdgcn_mfma_f32_16x16x32_bf16(pf[1][0], vf0, o[1][dc], 0, 0, 0);
      o[1][dc] = __builtin_amdgcn_mfma_f32_16x16x32_bf16(pf[1][1], vf1, o[1][dc], 0, 0, 0);
    }
    __syncthreads();
  }

  for (int im = 0; im < 2; ++im)
    for (int r = 0; r < 4; ++r) {
      float s = lr[im][r];
      for (int off = 8; off >= 1; off >>= 1) s += __shfl_xor(s, off, 64);
      float inv = 1.0f / s;
      int i = q0 + w * 32 + im * 16 + qc * 4 + r;
      for (int dc = 0; dc < 8; ++dc)
        ctx[(size_t)(b * SS + i) * EE + h * DD + dc * 16 + tm] =
            f32_to_bf16(o[im][dc][r] * inv);
    }
}

extern "C" void kernel_launch(void* const* d_in, const int* in_sizes, int n_in,
                              void* d_out, int out_size, void* d_ws, size_t ws_size,
                              hipStream_t stream) {
  const float* x  = (const float*)d_in[0];
  const float* Wq = (const float*)d_in[1];
  const float* Wk = (const float*)d_in[2];
  const float* Wv = (const float*)d_in[3];
  const float* Wo = (const float*)d_in[4];
  const float* bo = (const float*)d_in[5];
  float* out = (float*)d_out;

  const size_t XE = (size_t)BB * SS * EE;
  const size_t WE = (size_t)EE * EE;
  unsigned short* ws   = (unsigned short*)d_ws;
  unsigned short* xb   = ws;            // reused as ctx
  unsigned short* WqT  = xb + XE;       // WqT|WkT|WvT|WoT contiguous
  unsigned short* WoT  = WqT + 3 * WE;
  unsigned short* QKVb = WoT + WE;      // [B*S][3E] (V third unused now)
  unsigned short* Vt   = QKVb + 3 * XE;
  unsigned short* ctx  = xb;

  k_cast_bf16<<<XE / 1024, 256, 0, stream>>>(x, xb);
  k_transpose_w4<<<dim3(EE / 32, EE / 32, 4), 256, 0, stream>>>(Wq, Wk, Wv, Wo, WqT);

  dim3 gqkv(SE / 128, (BB * SS) / 128);  // (48, 32)
  k_gemm_bt<0><<<gqkv, 256, 0, stream>>>(xb, WqT, QKVb, nullptr, Vt, EE, SE);

  k_attn<<<dim3(BB * HH, SS / 128), 256, 0, stream>>>(QKVb, Vt, ctx);

  dim3 gg(EE / 128, (BB * SS) / 128);  // (16, 32)
  k_gemm_bt<1><<<gg, 256, 0, stream>>>(ctx, WoT, out, bo, nullptr, EE, EE);
}